// Round 1
// baseline (1189.208 us; speedup 1.0000x reference)
//
#include <hip/hip_runtime.h>
#include <math.h>

#define NB 8
#define NC 128
#define NHW 16384
#define NK 256
#define NT 64
#define SCALE_F 0.25f
#define LN_EPS 1e-6f

// XOR-swizzle on float4-group bits (float-offset bits 2..3) keyed by row bits 4..5.
// Breaks the "s, s+16, s+32, s+48 all same bank" 4-way conflict in attention reads.
#define SW(row, c) ((c) ^ ((((row) >> 4) & 3) << 2))

// ---------------------------------------------------------------------------
// Kernel 0: transpose Wq/Wk/Wv into WT[c][d], d = 0..63 q | 64..127 k | 128..255 v
// ---------------------------------------------------------------------------
__global__ __launch_bounds__(256) void wt_kernel(const float* __restrict__ Wq,
                                                 const float* __restrict__ Wk,
                                                 const float* __restrict__ Wv,
                                                 float* __restrict__ WT) {
  const int c = blockIdx.x;
  const int d = threadIdx.x;
  float v;
  if (d < 64)       v = Wq[d * NC + c];
  else if (d < 128) v = Wk[(d - 64) * NC + c];
  else              v = Wv[(d - 128) * NC + c];
  WT[c * 256 + d] = v;
}

// ---------------------------------------------------------------------------
// Kernel 1: fused LayerNorm (over C) + QKV projection.
// Block = 64 spatial positions of one batch. Writes:
//   qkv[b][pos][0..255]  (token-major, for gather)
//   accb[b][pos][0..127] = v  (scatter-mean base value)
//   den[b][pos] = 0
// ---------------------------------------------------------------------------
__global__ __launch_bounds__(256) void ln_proj_kernel(
    const float* __restrict__ x, const float* __restrict__ gamma,
    const float* __restrict__ beta, const float* __restrict__ WT,
    float* __restrict__ qkv, float* __restrict__ accb, float* __restrict__ den) {
  __shared__ __align__(16) float xc[NC][68];  // xn, c-major
  __shared__ __align__(16) float wt[NC][68];  // staged W chunk (64 dims), c-major
  const int t = threadIdx.x;
  const int b = blockIdx.y;
  const int pos0 = blockIdx.x * 64;

  // ---- load x tile: xc[c][p]  (coalesced over p, conflict-free LDS writes)
  {
    const int p = t & 63;
    const int cbase = (t >> 6) * 32;
    const float* xb = x + ((size_t)b * NC) * NHW + pos0 + p;
#pragma unroll
    for (int it = 0; it < 32; ++it) {
      const int c = cbase + it;
      xc[c][p] = xb[(size_t)c * NHW];
    }
  }
  if (t < 64) den[(size_t)b * NHW + pos0 + t] = 0.0f;
  __syncthreads();

  // ---- LayerNorm: 4 lanes per position, each reduces 32 channels
  {
    const int p = t >> 2;
    const int q = t & 3;
    float s = 0.f, ss = 0.f;
#pragma unroll
    for (int j = 0; j < 32; ++j) {
      const float v = xc[q * 32 + j][p];
      s += v;
      ss += v * v;
    }
    s += __shfl_xor(s, 1);  ss += __shfl_xor(ss, 1);
    s += __shfl_xor(s, 2);  ss += __shfl_xor(ss, 2);
    const float mu = s * (1.0f / 128.0f);
    const float var = ss * (1.0f / 128.0f) - mu * mu;
    const float rstd = rsqrtf(var + LN_EPS);
#pragma unroll
    for (int j = 0; j < 32; ++j) {
      const int c = q * 32 + j;
      xc[c][p] = gamma[c] * ((xc[c][p] - mu) * rstd) + beta[c];
    }
  }
  __syncthreads();

  // ---- projection: 4 chunks of 64 output dims; thread = 4 dims x 4 positions
  const int td = t & 15;   // dim group
  const int tp = t >> 4;   // pos group
  for (int ch = 0; ch < 4; ++ch) {
    // stage wt[c][dd] = WT[c][ch*64 + dd]
#pragma unroll
    for (int it = 0; it < 8; ++it) {
      const int f = t + it * 256;
      const int c = f >> 4;
      const int dd4 = (f & 15) * 4;
      *(float4*)&wt[c][dd4] = *(const float4*)&WT[c * 256 + ch * 64 + dd4];
    }
    __syncthreads();

    float acc[4][4] = {};
#pragma unroll 4
    for (int c = 0; c < NC; ++c) {
      const float4 w4 = *(const float4*)&wt[c][td * 4];
      const float4 x4 = *(const float4*)&xc[c][tp * 4];
      acc[0][0] = fmaf(x4.x, w4.x, acc[0][0]);
      acc[0][1] = fmaf(x4.x, w4.y, acc[0][1]);
      acc[0][2] = fmaf(x4.x, w4.z, acc[0][2]);
      acc[0][3] = fmaf(x4.x, w4.w, acc[0][3]);
      acc[1][0] = fmaf(x4.y, w4.x, acc[1][0]);
      acc[1][1] = fmaf(x4.y, w4.y, acc[1][1]);
      acc[1][2] = fmaf(x4.y, w4.z, acc[1][2]);
      acc[1][3] = fmaf(x4.y, w4.w, acc[1][3]);
      acc[2][0] = fmaf(x4.z, w4.x, acc[2][0]);
      acc[2][1] = fmaf(x4.z, w4.y, acc[2][1]);
      acc[2][2] = fmaf(x4.z, w4.z, acc[2][2]);
      acc[2][3] = fmaf(x4.z, w4.w, acc[2][3]);
      acc[3][0] = fmaf(x4.w, w4.x, acc[3][0]);
      acc[3][1] = fmaf(x4.w, w4.y, acc[3][1]);
      acc[3][2] = fmaf(x4.w, w4.z, acc[3][2]);
      acc[3][3] = fmaf(x4.w, w4.w, acc[3][3]);
    }

    const int dg = ch * 64 + td * 4;
#pragma unroll
    for (int j = 0; j < 4; ++j) {
      const int p = tp * 4 + j;
      const float4 o = make_float4(acc[j][0], acc[j][1], acc[j][2], acc[j][3]);
      *(float4*)&qkv[((size_t)b * NHW + pos0 + p) * 256 + dg] = o;
      if (ch >= 2) {
        *(float4*)&accb[((size_t)b * NHW + pos0 + p) * 128 + (dg - 128)] = o;
      }
    }
    __syncthreads();  // protect wt before next chunk
  }
}

// ---------------------------------------------------------------------------
// Kernel 2: per-(b,k) attention + atomic scatter.
// Block = 256 threads; thread = (token tt = t>>2, quarter q = t&3).
// ---------------------------------------------------------------------------
__global__ __launch_bounds__(256) void attn_kernel(
    const float* __restrict__ qkv, const int* __restrict__ indices,
    const float* __restrict__ sims, const float* __restrict__ jp,
    float* __restrict__ accb, float* __restrict__ den) {
  __shared__ __align__(16) float kqv[NT][260];
  __shared__ int idx_s[NT];
  __shared__ float w_s[NT];
  const int t = threadIdx.x;
  const int k = blockIdx.x;
  const int b = blockIdx.y;

  if (t < NT) {
    const int g = (b * NK + k) * NT + t;
    idx_s[t] = indices[g];
    w_s[t] = sims[g];
  }
  const float p = jp[b * NK + k];
  __syncthreads();

  // gather: one wave reads one token's contiguous 1 KB row
#pragma unroll
  for (int it = 0; it < 16; ++it) {
    const int f = t + it * 256;
    const int tok = f >> 6;
    const int c4 = (f & 63) << 2;
    const float4 v = *(const float4*)&qkv[((size_t)b * NHW + idx_s[tok]) * 256 + c4];
    *(float4*)&kqv[tok][SW(tok, c4)] = v;
  }
  __syncthreads();

  const int tt = t >> 2;
  const int q = t & 3;
  const float wtok = w_s[tt];
  const int itok = idx_s[tt];
  if (q == 0) atomicAdd(&den[(size_t)b * NHW + itok], wtok);

  for (int h = 0; h < 4; ++h) {
    // Q fragment for my token, this head (dims h*16 .. h*16+15)
    float qreg[16];
#pragma unroll
    for (int i4 = 0; i4 < 4; ++i4) {
      const float4 v = *(const float4*)&kqv[tt][SW(tt, h * 16 + i4 * 4)];
      qreg[i4 * 4 + 0] = v.x; qreg[i4 * 4 + 1] = v.y;
      qreg[i4 * 4 + 2] = v.z; qreg[i4 * 4 + 3] = v.w;
    }
    // scores for my 16 keys
    float sv[16];
#pragma unroll
    for (int j = 0; j < 16; ++j) {
      const int s = q * 16 + j;
      float dot = 0.f;
#pragma unroll
      for (int i4 = 0; i4 < 4; ++i4) {
        const float4 kv = *(const float4*)&kqv[s][SW(s, 64 + h * 16 + i4 * 4)];
        dot = fmaf(qreg[i4 * 4 + 0], kv.x, dot);
        dot = fmaf(qreg[i4 * 4 + 1], kv.y, dot);
        dot = fmaf(qreg[i4 * 4 + 2], kv.z, dot);
        dot = fmaf(qreg[i4 * 4 + 3], kv.w, dot);
      }
      sv[j] = dot * (SCALE_F * p);
    }
    // softmax over 64 keys (16 local + 4-lane butterfly)
    float m = sv[0];
#pragma unroll
    for (int j = 1; j < 16; ++j) m = fmaxf(m, sv[j]);
    m = fmaxf(m, __shfl_xor(m, 1));
    m = fmaxf(m, __shfl_xor(m, 2));
    float sum = 0.f;
#pragma unroll
    for (int j = 0; j < 16; ++j) {
      sv[j] = __expf(sv[j] - m);
      sum += sv[j];
    }
    sum += __shfl_xor(sum, 1);
    sum += __shfl_xor(sum, 2);
    const float inv = 1.0f / sum;

    // PV: partial over my 16 keys, all 32 v-channels of this head
    float oc[32] = {};
#pragma unroll
    for (int j = 0; j < 16; ++j) {
      const int s = q * 16 + j;
      const float pj = sv[j] * inv;
#pragma unroll
      for (int c4 = 0; c4 < 8; ++c4) {
        const float4 v4 = *(const float4*)&kqv[s][SW(s, 128 + h * 32 + c4 * 4)];
        oc[c4 * 4 + 0] = fmaf(pj, v4.x, oc[c4 * 4 + 0]);
        oc[c4 * 4 + 1] = fmaf(pj, v4.y, oc[c4 * 4 + 1]);
        oc[c4 * 4 + 2] = fmaf(pj, v4.z, oc[c4 * 4 + 2]);
        oc[c4 * 4 + 3] = fmaf(pj, v4.w, oc[c4 * 4 + 3]);
      }
    }
    // 4-lane butterfly all-reduce (static indices only — no scratch spill)
#pragma unroll
    for (int c = 0; c < 32; ++c) {
      oc[c] += __shfl_xor(oc[c], 1);
      oc[c] += __shfl_xor(oc[c], 2);
    }
    if (q == 0) {
      float* dst = &accb[((size_t)b * NHW + itok) * 128 + h * 32];
#pragma unroll
      for (int c = 0; c < 32; ++c) atomicAdd(&dst[c], wtok * oc[c]);
    }
  }
}

// ---------------------------------------------------------------------------
// Kernel 3: res[b][c][pos] = accb[b][pos][c] / (1 + den[b][pos])  (LDS transpose)
// ---------------------------------------------------------------------------
__global__ __launch_bounds__(256) void final_kernel(
    const float* __restrict__ accb, const float* __restrict__ den,
    float* __restrict__ out) {
  __shared__ float tile[64][33];
  const int t = threadIdx.x;
  const int pos0 = blockIdx.x * 64;
  const int c0 = blockIdx.y * 32;
  const int b = blockIdx.z;
  {
    const int cc = t & 31;
    const int p0 = t >> 5;
#pragma unroll
    for (int it = 0; it < 8; ++it) {
      const int pp = p0 + it * 8;
      tile[pp][cc] = accb[((size_t)b * NHW + pos0 + pp) * 128 + c0 + cc];
    }
  }
  __syncthreads();
  {
    const int px = t & 63;
    const int cy0 = t >> 6;
    const float inv = 1.0f / (1.0f + den[(size_t)b * NHW + pos0 + px]);
#pragma unroll
    for (int it = 0; it < 8; ++it) {
      const int cy = cy0 + it * 4;
      out[((size_t)b * NC + c0 + cy) * NHW + pos0 + px] = tile[px][cy] * inv;
    }
  }
}

// ---------------------------------------------------------------------------
extern "C" void kernel_launch(void* const* d_in, const int* in_sizes, int n_in,
                              void* d_out, int out_size, void* d_ws, size_t ws_size,
                              hipStream_t stream) {
  (void)in_sizes; (void)n_in; (void)out_size; (void)ws_size;
  const float* x     = (const float*)d_in[0];
  const float* jp    = (const float*)d_in[1];
  const float* sims  = (const float*)d_in[2];
  const float* gamma = (const float*)d_in[3];
  const float* beta  = (const float*)d_in[4];
  const float* Wq    = (const float*)d_in[5];
  const float* Wk    = (const float*)d_in[6];
  const float* Wv    = (const float*)d_in[7];
  const int* indices = (const int*)d_in[8];
  float* out = (float*)d_out;

  char* ws = (char*)d_ws;
  float* qkv  = (float*)ws;                                       // [B][HW][256]
  float* accb = (float*)(ws + (size_t)NB * NHW * 256 * 4);        // [B][HW][128]
  float* den  = (float*)(ws + (size_t)NB * NHW * 384 * 4);        // [B][HW]
  float* WT   = (float*)(ws + (size_t)NB * NHW * 385 * 4);        // [128][256]

  wt_kernel<<<dim3(NC), 256, 0, stream>>>(Wq, Wk, Wv, WT);
  ln_proj_kernel<<<dim3(NHW / 64, NB), 256, 0, stream>>>(x, gamma, beta, WT,
                                                         qkv, accb, den);
  attn_kernel<<<dim3(NK, NB), 256, 0, stream>>>(qkv, indices, sims, jp, accb, den);
  final_kernel<<<dim3(NHW / 64, NC / 32, NB), 256, 0, stream>>>(accb, den, out);
}

// Round 2
// 456.900 us; speedup vs baseline: 2.6028x; 2.6028x over previous
//
#include <hip/hip_runtime.h>
#include <hip/hip_bf16.h>
#include <math.h>

#define NB 8
#define NC 128
#define NHW 16384
#define NK 256
#define NT 64
#define SCALE_F 0.25f
#define LN_EPS 1e-6f

// XOR-swizzle on float4-group bits (float-offset bits 2..3) keyed by row bits 4..5.
#define SW(row, c) ((c) ^ ((((row) >> 4) & 3) << 2))

// ---------------------------------------------------------------------------
// Kernel 0: transpose Wq/Wk/Wv into WT[c][d], d = 0..63 q | 64..127 k | 128..255 v
// ---------------------------------------------------------------------------
__global__ __launch_bounds__(256) void wt_kernel(const float* __restrict__ Wq,
                                                 const float* __restrict__ Wk,
                                                 const float* __restrict__ Wv,
                                                 float* __restrict__ WT) {
  const int c = blockIdx.x;
  const int d = threadIdx.x;
  float v;
  if (d < 64)       v = Wq[d * NC + c];
  else if (d < 128) v = Wk[(d - 64) * NC + c];
  else              v = Wv[(d - 128) * NC + c];
  WT[c * 256 + d] = v;
}

// ---------------------------------------------------------------------------
// index-inversion helpers: cnt -> exclusive scan -> fill (CSR per batch)
// ---------------------------------------------------------------------------
__global__ __launch_bounds__(256) void zero_cnt_kernel(int* __restrict__ cnt) {
  cnt[blockIdx.x * 256 + threadIdx.x] = 0;  // grid 512 covers B*HW = 131072
}

__global__ __launch_bounds__(256) void count_kernel(const int* __restrict__ indices,
                                                    int* __restrict__ cnt) {
  const int g = blockIdx.x * 256 + threadIdx.x;  // grid 512: B*K*T tokens
  const int b = g >> 14;
  atomicAdd(&cnt[(b << 14) + indices[g]], 1);
}

// one block per batch: inclusive Hillis-Steele over 256 chunk sums, 64 elems/thread
__global__ __launch_bounds__(256) void scan_kernel(const int* __restrict__ cnt,
                                                   int* __restrict__ offs) {
  const int b = blockIdx.x, t = threadIdx.x;
  const int base = (b << 14) + t * 64;
  int s = 0;
  for (int j = 0; j < 64; ++j) s += cnt[base + j];
  __shared__ int sums[256];
  sums[t] = s;
  __syncthreads();
  for (int off = 1; off < 256; off <<= 1) {
    int v = (t >= off) ? sums[t - off] : 0;
    __syncthreads();
    sums[t] += v;
    __syncthreads();
  }
  int run = (t == 0) ? 0 : sums[t - 1];
  for (int j = 0; j < 64; ++j) {
    offs[base + j] = run;
    run += cnt[base + j];
  }
}

// slot = offs[pos]++ (offs becomes inclusive-end; start recovered as end-cnt)
__global__ __launch_bounds__(256) void fill_kernel(const int* __restrict__ indices,
                                                   int* __restrict__ offs,
                                                   int* __restrict__ list) {
  const int g = blockIdx.x * 256 + threadIdx.x;
  const int b = g >> 14;
  const int tok = g & 16383;
  const int pos = indices[g];
  const int slot = atomicAdd(&offs[(b << 14) + pos], 1);
  list[(b << 14) + slot] = tok;
}

// ---------------------------------------------------------------------------
// Kernel 1: fused LayerNorm (over C) + QKV projection. qkv[b][pos][0..255].
// ---------------------------------------------------------------------------
__global__ __launch_bounds__(256) void ln_proj_kernel(
    const float* __restrict__ x, const float* __restrict__ gamma,
    const float* __restrict__ beta, const float* __restrict__ WT,
    float* __restrict__ qkv) {
  __shared__ __align__(16) float xc[NC][68];
  __shared__ __align__(16) float wt[NC][68];
  const int t = threadIdx.x;
  const int b = blockIdx.y;
  const int pos0 = blockIdx.x * 64;

  {
    const int p = t & 63;
    const int cbase = (t >> 6) * 32;
    const float* xb = x + ((size_t)b * NC) * NHW + pos0 + p;
#pragma unroll
    for (int it = 0; it < 32; ++it) {
      const int c = cbase + it;
      xc[c][p] = xb[(size_t)c * NHW];
    }
  }
  __syncthreads();

  {
    const int p = t >> 2;
    const int q = t & 3;
    float s = 0.f, ss = 0.f;
#pragma unroll
    for (int j = 0; j < 32; ++j) {
      const float v = xc[q * 32 + j][p];
      s += v;
      ss += v * v;
    }
    s += __shfl_xor(s, 1);  ss += __shfl_xor(ss, 1);
    s += __shfl_xor(s, 2);  ss += __shfl_xor(ss, 2);
    const float mu = s * (1.0f / 128.0f);
    const float var = ss * (1.0f / 128.0f) - mu * mu;
    const float rstd = rsqrtf(var + LN_EPS);
#pragma unroll
    for (int j = 0; j < 32; ++j) {
      const int c = q * 32 + j;
      xc[c][p] = gamma[c] * ((xc[c][p] - mu) * rstd) + beta[c];
    }
  }
  __syncthreads();

  const int td = t & 15;
  const int tp = t >> 4;
  for (int ch = 0; ch < 4; ++ch) {
#pragma unroll
    for (int it = 0; it < 8; ++it) {
      const int f = t + it * 256;
      const int c = f >> 4;
      const int dd4 = (f & 15) * 4;
      *(float4*)&wt[c][dd4] = *(const float4*)&WT[c * 256 + ch * 64 + dd4];
    }
    __syncthreads();

    float acc[4][4] = {};
#pragma unroll 4
    for (int c = 0; c < NC; ++c) {
      const float4 w4 = *(const float4*)&wt[c][td * 4];
      const float4 x4 = *(const float4*)&xc[c][tp * 4];
      acc[0][0] = fmaf(x4.x, w4.x, acc[0][0]);
      acc[0][1] = fmaf(x4.x, w4.y, acc[0][1]);
      acc[0][2] = fmaf(x4.x, w4.z, acc[0][2]);
      acc[0][3] = fmaf(x4.x, w4.w, acc[0][3]);
      acc[1][0] = fmaf(x4.y, w4.x, acc[1][0]);
      acc[1][1] = fmaf(x4.y, w4.y, acc[1][1]);
      acc[1][2] = fmaf(x4.y, w4.z, acc[1][2]);
      acc[1][3] = fmaf(x4.y, w4.w, acc[1][3]);
      acc[2][0] = fmaf(x4.z, w4.x, acc[2][0]);
      acc[2][1] = fmaf(x4.z, w4.y, acc[2][1]);
      acc[2][2] = fmaf(x4.z, w4.z, acc[2][2]);
      acc[2][3] = fmaf(x4.z, w4.w, acc[2][3]);
      acc[3][0] = fmaf(x4.w, w4.x, acc[3][0]);
      acc[3][1] = fmaf(x4.w, w4.y, acc[3][1]);
      acc[3][2] = fmaf(x4.w, w4.z, acc[3][2]);
      acc[3][3] = fmaf(x4.w, w4.w, acc[3][3]);
    }

    const int dg = ch * 64 + td * 4;
#pragma unroll
    for (int j = 0; j < 4; ++j) {
      const int p = tp * 4 + j;
      *(float4*)&qkv[((size_t)b * NHW + pos0 + p) * 256 + dg] =
          make_float4(acc[j][0], acc[j][1], acc[j][2], acc[j][3]);
    }
    __syncthreads();
  }
}

// ---------------------------------------------------------------------------
// Kernel 2: per-(b,k) attention; DENSE bf16 write of w*out (no atomics).
// thread = (token tt = t>>2, quarter q = t&3); lane q owns output chans q*8..q*8+7.
// ---------------------------------------------------------------------------
__global__ __launch_bounds__(256) void attn_kernel(
    const float* __restrict__ qkv, const int* __restrict__ indices,
    const float* __restrict__ sims, const float* __restrict__ jp,
    ushort* __restrict__ wout) {
  __shared__ __align__(16) float kqv[NT][260];
  __shared__ int idx_s[NT];
  __shared__ float w_s[NT];
  const int t = threadIdx.x;
  const int k = blockIdx.x;
  const int b = blockIdx.y;
  const size_t bh = (size_t)b << 14;

  if (t < NT) {
    const int g = (b * NK + k) * NT + t;
    idx_s[t] = indices[g];
    w_s[t] = sims[g];
  }
  const float p = jp[b * NK + k];
  __syncthreads();

#pragma unroll
  for (int it = 0; it < 16; ++it) {
    const int f = t + it * 256;
    const int tok = f >> 6;
    const int c4 = (f & 63) << 2;
    const float4 v = *(const float4*)&qkv[(bh + idx_s[tok]) * 256 + c4];
    *(float4*)&kqv[tok][SW(tok, c4)] = v;
  }
  __syncthreads();

  const int tt = t >> 2;
  const int q = t & 3;
  const float wtok = w_s[tt];

  for (int h = 0; h < 4; ++h) {
    float qreg[16];
#pragma unroll
    for (int i4 = 0; i4 < 4; ++i4) {
      const float4 v = *(const float4*)&kqv[tt][SW(tt, h * 16 + i4 * 4)];
      qreg[i4 * 4 + 0] = v.x; qreg[i4 * 4 + 1] = v.y;
      qreg[i4 * 4 + 2] = v.z; qreg[i4 * 4 + 3] = v.w;
    }
    float sv[16];
#pragma unroll
    for (int j = 0; j < 16; ++j) {
      const int s = q * 16 + j;
      float dot = 0.f;
#pragma unroll
      for (int i4 = 0; i4 < 4; ++i4) {
        const float4 kv = *(const float4*)&kqv[s][SW(s, 64 + h * 16 + i4 * 4)];
        dot = fmaf(qreg[i4 * 4 + 0], kv.x, dot);
        dot = fmaf(qreg[i4 * 4 + 1], kv.y, dot);
        dot = fmaf(qreg[i4 * 4 + 2], kv.z, dot);
        dot = fmaf(qreg[i4 * 4 + 3], kv.w, dot);
      }
      sv[j] = dot * (SCALE_F * p);
    }
    // softmax over 64 keys (16 local + 4-lane butterfly)
    float m = sv[0];
#pragma unroll
    for (int j = 1; j < 16; ++j) m = fmaxf(m, sv[j]);
    m = fmaxf(m, __shfl_xor(m, 1));
    m = fmaxf(m, __shfl_xor(m, 2));
    float sum = 0.f;
#pragma unroll
    for (int j = 0; j < 16; ++j) {
      sv[j] = __expf(sv[j] - m);
      sum += sv[j];
    }
    sum += __shfl_xor(sum, 1);
    sum += __shfl_xor(sum, 2);
    const float inv = 1.0f / sum;
#pragma unroll
    for (int j = 0; j < 16; ++j) sv[j] *= inv;

    // PV: lane q owns channels h*32 + q*8 .. +7 over ALL 64 keys.
    // Probabilities redistributed via static shuffles: pr[e] = P of key (q^e)*16+jj.
    float oc8[8] = {};
#pragma unroll
    for (int jj = 0; jj < 16; ++jj) {
      float pr[4];
      pr[0] = sv[jj];
      pr[1] = __shfl_xor(sv[jj], 1);
      pr[2] = __shfl_xor(sv[jj], 2);
      pr[3] = __shfl_xor(sv[jj], 3);
#pragma unroll
      for (int e = 0; e < 4; ++e) {
        const int s = (q ^ e) * 16 + jj;
        const float4 v0 = *(const float4*)&kqv[s][SW(s, 128 + h * 32 + q * 8)];
        const float4 v1 = *(const float4*)&kqv[s][SW(s, 128 + h * 32 + q * 8 + 4)];
        oc8[0] = fmaf(pr[e], v0.x, oc8[0]);
        oc8[1] = fmaf(pr[e], v0.y, oc8[1]);
        oc8[2] = fmaf(pr[e], v0.z, oc8[2]);
        oc8[3] = fmaf(pr[e], v0.w, oc8[3]);
        oc8[4] = fmaf(pr[e], v1.x, oc8[4]);
        oc8[5] = fmaf(pr[e], v1.y, oc8[5]);
        oc8[6] = fmaf(pr[e], v1.z, oc8[6]);
        oc8[7] = fmaf(pr[e], v1.w, oc8[7]);
      }
    }
    // pack w*oc8 to bf16 and store 16B (wave covers 64B contiguous per token)
    union { __hip_bfloat162 h2; unsigned int u; } u0, u1, u2, u3;
    u0.h2 = __float22bfloat162_rn(make_float2(oc8[0] * wtok, oc8[1] * wtok));
    u1.h2 = __float22bfloat162_rn(make_float2(oc8[2] * wtok, oc8[3] * wtok));
    u2.h2 = __float22bfloat162_rn(make_float2(oc8[4] * wtok, oc8[5] * wtok));
    u3.h2 = __float22bfloat162_rn(make_float2(oc8[6] * wtok, oc8[7] * wtok));
    uint4 pk;
    pk.x = u0.u; pk.y = u1.u; pk.z = u2.u; pk.w = u3.u;
    ushort* wr = wout + ((bh + (size_t)k * NT + tt) << 7) + h * 32 + q * 8;
    *(uint4*)wr = pk;
  }
}

// ---------------------------------------------------------------------------
// Kernel 3: gather-based finalize.
// res[p][c] = (v[p][c] + sum_tok wout[tok][c]) / (1 + sum_tok sims[tok]); transpose-write.
// ---------------------------------------------------------------------------
__global__ __launch_bounds__(256) void final_gather(
    const float* __restrict__ qkv, const ushort* __restrict__ wout,
    const float* __restrict__ sims, const int* __restrict__ cnt,
    const int* __restrict__ offs, const int* __restrict__ list,
    float* __restrict__ out) {
  __shared__ __align__(16) float res[64][132];
  __shared__ float invd[64];
  __shared__ int cnt_s[64], st_s[64];
  const int t = threadIdx.x;
  const int pos0 = blockIdx.x * 64;
  const int b = blockIdx.y;
  const size_t bh = (size_t)b << 14;

  if (t < 64) {
    const int p = pos0 + t;
    const int c = cnt[bh + p];
    cnt_s[t] = c;
    st_s[t] = offs[bh + p] - c;  // offs is inclusive-end after fill_kernel
  }
  // load v rows (qkv channels 128..255) into res
#pragma unroll
  for (int it = 0; it < 8; ++it) {
    const int f = t + it * 256;
    const int row = f >> 5;
    const int c4 = (f & 31) * 4;
    *(float4*)&res[row][c4] =
        *(const float4*)&qkv[(bh + pos0 + row) * 256 + 128 + c4];
  }
  __syncthreads();

  if (t < 64) {
    float s = 0.f;
    const int n = cnt_s[t], st = st_s[t];
    for (int j = 0; j < n; ++j) {
      const int tok = list[bh + st + j];
      s += sims[bh + tok];
    }
    invd[t] = 1.0f / (1.0f + s);
  }
  __syncthreads();

  {
    const int w = t >> 6, l = t & 63;
    for (int p16 = 0; p16 < 16; ++p16) {
      const int p = w * 16 + p16;
      const int n = cnt_s[p], st = st_s[p];
      if (n) {
        float2 a = *(float2*)&res[p][l * 2];
        for (int j = 0; j < n; ++j) {
          const int tok = list[bh + st + j];
          const __hip_bfloat162 h2 =
              ((const __hip_bfloat162*)(wout + ((bh + tok) << 7)))[l];
          const float2 f2 = __bfloat1622float2(h2);
          a.x += f2.x;
          a.y += f2.y;
        }
        res[p][l * 2]     = a.x;
        res[p][l * 2 + 1] = a.y;
      }
    }
  }
  __syncthreads();

  {
    const int px = t & 63;
    const int cg = t >> 6;
    const float inv = invd[px];
#pragma unroll
    for (int it = 0; it < 32; ++it) {
      const int c = cg * 32 + it;
      out[(bh << 7) + (size_t)c * NHW + pos0 + px] = res[px][c] * inv;
    }
  }
}

// ---------------------------------------------------------------------------
extern "C" void kernel_launch(void* const* d_in, const int* in_sizes, int n_in,
                              void* d_out, int out_size, void* d_ws, size_t ws_size,
                              hipStream_t stream) {
  (void)in_sizes; (void)n_in; (void)out_size; (void)ws_size;
  const float* x     = (const float*)d_in[0];
  const float* jp    = (const float*)d_in[1];
  const float* sims  = (const float*)d_in[2];
  const float* gamma = (const float*)d_in[3];
  const float* beta  = (const float*)d_in[4];
  const float* Wq    = (const float*)d_in[5];
  const float* Wk    = (const float*)d_in[6];
  const float* Wv    = (const float*)d_in[7];
  const int* indices = (const int*)d_in[8];
  float* out = (float*)d_out;

  char* ws = (char*)d_ws;
  float*  qkv  = (float*)ws;                          // [B][HW][256] 134.2MB
  ushort* wout = (ushort*)(ws + 134217728);           // [B][HW][128] bf16 33.5MB
  float*  WT   = (float*)(ws + 167772160);            // [128][256]   0.13MB
  int*    cnt  = (int*)(ws + 167903232);              // [B][HW]
  int*    offs = (int*)(ws + 168427520);              // [B][HW]
  int*    list = (int*)(ws + 168951808);              // [B][HW]

  zero_cnt_kernel<<<dim3(512), 256, 0, stream>>>(cnt);
  count_kernel<<<dim3(512), 256, 0, stream>>>(indices, cnt);
  wt_kernel<<<dim3(NC), 256, 0, stream>>>(Wq, Wk, Wv, WT);
  ln_proj_kernel<<<dim3(NHW / 64, NB), 256, 0, stream>>>(x, gamma, beta, WT, qkv);
  scan_kernel<<<dim3(NB), 256, 0, stream>>>(cnt, offs);
  fill_kernel<<<dim3(512), 256, 0, stream>>>(indices, offs, list);
  attn_kernel<<<dim3(NK, NB), 256, 0, stream>>>(qkv, indices, sims, jp, wout);
  final_gather<<<dim3(NHW / 64, NB), 256, 0, stream>>>(qkv, wout, sims, cnt,
                                                       offs, list, out);
}

// Round 4
// 345.596 us; speedup vs baseline: 3.4410x; 1.3221x over previous
//
#include <hip/hip_runtime.h>
#include <hip/hip_bf16.h>
#include <math.h>

#define NB 8
#define NC 128
#define NHW 16384
#define NK 256
#define NT 64
#define SCALE_F 0.25f
#define LN_EPS 1e-6f

typedef short s16x8 __attribute__((ext_vector_type(8)));
typedef float f32x16 __attribute__((ext_vector_type(16)));

union FragU { unsigned u[4]; s16x8 s; };

static __device__ inline unsigned pack2bf(float a, float b) {
  union { __hip_bfloat162 h; unsigned u; } x;
  x.h = __float22bfloat162_rn(make_float2(a, b));
  return x.u;
}
static __device__ inline float bflo(unsigned u) { return __uint_as_float(u << 16); }
static __device__ inline float bfhi(unsigned u) { return __uint_as_float(u & 0xffff0000u); }

// ---------------------------------------------------------------------------
// Kernel 0: transpose Wq/Wk/Wv into WT[c][d] (fp32; consumed by ln_proj)
// ---------------------------------------------------------------------------
__global__ __launch_bounds__(256) void wt_kernel(const float* __restrict__ Wq,
                                                 const float* __restrict__ Wk,
                                                 const float* __restrict__ Wv,
                                                 float* __restrict__ WT) {
  const int c = blockIdx.x;
  const int d = threadIdx.x;
  float v;
  if (d < 64)       v = Wq[d * NC + c];
  else if (d < 128) v = Wk[(d - 64) * NC + c];
  else              v = Wv[(d - 128) * NC + c];
  WT[c * 256 + d] = v;
}

// ---------------------------------------------------------------------------
// index-inversion helpers: cnt -> scan -> fill (CSR per batch)
// ---------------------------------------------------------------------------
__global__ __launch_bounds__(256) void zero_cnt_kernel(int* __restrict__ cnt) {
  cnt[blockIdx.x * 256 + threadIdx.x] = 0;
}

__global__ __launch_bounds__(256) void count_kernel(const int* __restrict__ indices,
                                                    int* __restrict__ cnt) {
  const int g = blockIdx.x * 256 + threadIdx.x;
  const int b = g >> 14;
  atomicAdd(&cnt[(b << 14) + indices[g]], 1);
}

__global__ __launch_bounds__(256) void scan_kernel(const int* __restrict__ cnt,
                                                   int* __restrict__ offs) {
  const int b = blockIdx.x, t = threadIdx.x;
  const int base = (b << 14) + t * 64;
  int s = 0;
  for (int j = 0; j < 64; ++j) s += cnt[base + j];
  __shared__ int sums[256];
  sums[t] = s;
  __syncthreads();
  for (int off = 1; off < 256; off <<= 1) {
    int v = (t >= off) ? sums[t - off] : 0;
    __syncthreads();
    sums[t] += v;
    __syncthreads();
  }
  int run = (t == 0) ? 0 : sums[t - 1];
  for (int j = 0; j < 64; ++j) {
    offs[base + j] = run;
    run += cnt[base + j];
  }
}

__global__ __launch_bounds__(256) void fill_kernel(const int* __restrict__ indices,
                                                   int* __restrict__ offs,
                                                   int* __restrict__ list) {
  const int g = blockIdx.x * 256 + threadIdx.x;
  const int b = g >> 14;
  const int tok = g & 16383;
  const int pos = indices[g];
  const int slot = atomicAdd(&offs[(b << 14) + pos], 1);
  list[(b << 14) + slot] = tok;
}

// ---------------------------------------------------------------------------
// Kernel 1: fused LayerNorm + QKV projection. Writes qkvb[b][pos][0..255] bf16.
// ---------------------------------------------------------------------------
__global__ __launch_bounds__(256) void ln_proj_kernel(
    const float* __restrict__ x, const float* __restrict__ gamma,
    const float* __restrict__ beta, const float* __restrict__ WT,
    ushort* __restrict__ qkvb) {
  __shared__ __align__(16) float xc[NC][68];
  __shared__ __align__(16) float wt[NC][68];
  const int t = threadIdx.x;
  const int b = blockIdx.y;
  const int pos0 = blockIdx.x * 64;

  {
    const int p = t & 63;
    const int cbase = (t >> 6) * 32;
    const float* xb = x + ((size_t)b * NC) * NHW + pos0 + p;
#pragma unroll
    for (int it = 0; it < 32; ++it) {
      const int c = cbase + it;
      xc[c][p] = xb[(size_t)c * NHW];
    }
  }
  __syncthreads();

  {
    const int p = t >> 2;
    const int q = t & 3;
    float s = 0.f, ss = 0.f;
#pragma unroll
    for (int j = 0; j < 32; ++j) {
      const float v = xc[q * 32 + j][p];
      s += v;
      ss += v * v;
    }
    s += __shfl_xor(s, 1);  ss += __shfl_xor(ss, 1);
    s += __shfl_xor(s, 2);  ss += __shfl_xor(ss, 2);
    const float mu = s * (1.0f / 128.0f);
    const float var = ss * (1.0f / 128.0f) - mu * mu;
    const float rstd = rsqrtf(var + LN_EPS);
#pragma unroll
    for (int j = 0; j < 32; ++j) {
      const int c = q * 32 + j;
      xc[c][p] = gamma[c] * ((xc[c][p] - mu) * rstd) + beta[c];
    }
  }
  __syncthreads();

  const int td = t & 15;
  const int tp = t >> 4;
  for (int ch = 0; ch < 4; ++ch) {
#pragma unroll
    for (int it = 0; it < 8; ++it) {
      const int f = t + it * 256;
      const int c = f >> 4;
      const int dd4 = (f & 15) * 4;
      *(float4*)&wt[c][dd4] = *(const float4*)&WT[c * 256 + ch * 64 + dd4];
    }
    __syncthreads();

    float acc[4][4] = {};
#pragma unroll 4
    for (int c = 0; c < NC; ++c) {
      const float4 w4 = *(const float4*)&wt[c][td * 4];
      const float4 x4 = *(const float4*)&xc[c][tp * 4];
      acc[0][0] = fmaf(x4.x, w4.x, acc[0][0]);
      acc[0][1] = fmaf(x4.x, w4.y, acc[0][1]);
      acc[0][2] = fmaf(x4.x, w4.z, acc[0][2]);
      acc[0][3] = fmaf(x4.x, w4.w, acc[0][3]);
      acc[1][0] = fmaf(x4.y, w4.x, acc[1][0]);
      acc[1][1] = fmaf(x4.y, w4.y, acc[1][1]);
      acc[1][2] = fmaf(x4.y, w4.z, acc[1][2]);
      acc[1][3] = fmaf(x4.y, w4.w, acc[1][3]);
      acc[2][0] = fmaf(x4.z, w4.x, acc[2][0]);
      acc[2][1] = fmaf(x4.z, w4.y, acc[2][1]);
      acc[2][2] = fmaf(x4.z, w4.z, acc[2][2]);
      acc[2][3] = fmaf(x4.z, w4.w, acc[2][3]);
      acc[3][0] = fmaf(x4.w, w4.x, acc[3][0]);
      acc[3][1] = fmaf(x4.w, w4.y, acc[3][1]);
      acc[3][2] = fmaf(x4.w, w4.z, acc[3][2]);
      acc[3][3] = fmaf(x4.w, w4.w, acc[3][3]);
    }

    const int dg = ch * 64 + td * 4;
#pragma unroll
    for (int j = 0; j < 4; ++j) {
      const int p = tp * 4 + j;
      uint2 pk2;
      pk2.x = pack2bf(acc[j][0], acc[j][1]);
      pk2.y = pack2bf(acc[j][2], acc[j][3]);
      *(uint2*)&qkvb[((size_t)b * NHW + pos0 + p) * 256 + dg] = pk2;
    }
    __syncthreads();
  }
}

// ---------------------------------------------------------------------------
// Kernel 2: MFMA attention. Block = (b,k); wave = head h.
// S^T = mfma(K, Q^T) [swapped -> softmax keys land in-lane]; P repacked in-reg;
// O^T = mfma(V^T, P^T); dense bf16 store of w*out.
// LDS: kqv[64 tok][256 ch] bf16, 16B-slot XOR swizzle: slot ^= (row&7).
// ---------------------------------------------------------------------------
__global__ __launch_bounds__(256) void attn_kernel(
    const ushort* __restrict__ qkvb, const int* __restrict__ indices,
    const float* __restrict__ sims, const float* __restrict__ jp,
    ushort* __restrict__ wout) {
  __shared__ __align__(16) ushort kqv[64 * 256];
  __shared__ int idx_s[NT];
  __shared__ float w_s[NT];
  const int t = threadIdx.x;
  const int k = blockIdx.x;
  const int b = blockIdx.y;
  const size_t bh = (size_t)b << 14;

  if (t < NT) {
    const int g = (b * NK + k) * NT + t;
    idx_s[t] = indices[g];
    w_s[t] = sims[g];
  }
  const float sp = SCALE_F * jp[b * NK + k];
  __syncthreads();

  // ---- gather: one wave copies one token row (512B) per iter, swizzled into LDS
  {
    const int w = t >> 6, l = t & 63;
    const int c4 = l * 4;
    const int slot = c4 >> 3;
    const int lowb = (c4 & 7) * 2;
#pragma unroll
    for (int it = 0; it < 16; ++it) {
      const int tok = w * 16 + it;
      const uint2 v = *(const uint2*)&qkvb[(bh + idx_s[tok]) * 256 + c4];
      *(uint2*)((char*)kqv + tok * 512 + ((slot ^ (tok & 7)) << 4) + lowb) = v;
    }
  }
  __syncthreads();

  const int h = t >> 6;
  const int l = t & 63;
  const int c = l & 31;   // MFMA column (tok for S^T, ch for O^T)
  const int hl = l >> 5;

  // ---- Q/K fragments (A/B-frag layout: row/col = l&31, k = 8*(l>>5)+j)
  s16x8 qf[2], kf[2];
  {
    const int slotq = h * 2 + hl;
    const int slotk = 8 + h * 2 + hl;
#pragma unroll
    for (int tt = 0; tt < 2; ++tt) {
      const int row = 32 * tt + c;
      qf[tt] = *(const s16x8*)((const char*)kqv + row * 512 + ((slotq ^ (row & 7)) << 4));
    }
#pragma unroll
    for (int at = 0; at < 2; ++at) {
      const int row = 32 * at + c;
      kf[at] = *(const s16x8*)((const char*)kqv + row * 512 + ((slotk ^ (row & 7)) << 4));
    }
  }

  // ---- QK^T (swapped): sacc[at][tt] = S^T tile [key=32at+R(reg,hl)][tok=32tt+c]
  f32x16 sacc[2][2];
#pragma unroll
  for (int at = 0; at < 2; ++at)
#pragma unroll
    for (int tt = 0; tt < 2; ++tt) {
#pragma unroll
      for (int i = 0; i < 16; ++i) sacc[at][tt][i] = 0.f;
      sacc[at][tt] = __builtin_amdgcn_mfma_f32_32x32x16_bf16(kf[at], qf[tt], sacc[at][tt], 0, 0, 0);
    }

  // ---- softmax over keys (32 in-lane + xor32), fold sims weight into P
  // pkv[at][tt][pi] (for this hl) = keys 32*at + 8*(pi>>1) + 4*hl + 2*(pi&1) + {0,1}
  unsigned pkv[2][2][8];
#pragma unroll
  for (int tt = 0; tt < 2; ++tt) {
    float m = -1e30f;
#pragma unroll
    for (int at = 0; at < 2; ++at)
#pragma unroll
      for (int i = 0; i < 16; ++i) m = fmaxf(m, sacc[at][tt][i]);
    m = fmaxf(m, __shfl_xor(m, 32));
    float sum = 0.f;
#pragma unroll
    for (int at = 0; at < 2; ++at)
#pragma unroll
      for (int i = 0; i < 16; ++i) {
        const float e = __expf((sacc[at][tt][i] - m) * sp);
        sacc[at][tt][i] = e;
        sum += e;
      }
    sum += __shfl_xor(sum, 32);
    const float inv = w_s[32 * tt + c] / sum;
#pragma unroll
    for (int at = 0; at < 2; ++at)
#pragma unroll
      for (int pi = 0; pi < 8; ++pi)
        pkv[at][tt][pi] = pack2bf(sacc[at][tt][2 * pi] * inv, sacc[at][tt][2 * pi + 1] * inv);
  }

  // ---- PV: oac[tt] = O^T tile [ch'=R(reg,hl)][tok=32tt+c]
  f32x16 oac[2];
#pragma unroll
  for (int tt = 0; tt < 2; ++tt)
#pragma unroll
    for (int i = 0; i < 16; ++i) oac[tt][i] = 0.f;

  const int slotv = 16 + h * 4 + (c >> 3);
  const int lowv = (c & 7) * 2;
#pragma unroll
  for (int ks = 0; ks < 4; ++ks) {
    const int at = ks >> 1;
    const int ksb = 16 * ks + 8 * hl;
    // V^T A-frag: elem j = V[key=ksb+j][h*32+c]; (ksb+j)&7 == j so swizzle XOR = j
    FragU vf;
#pragma unroll
    for (int jj = 0; jj < 4; ++jj) {
      const unsigned lo =
          *(const ushort*)((const char*)kqv + (ksb + 2 * jj) * 512 + ((slotv ^ (2 * jj)) << 4) + lowv);
      const unsigned hi =
          *(const ushort*)((const char*)kqv + (ksb + 2 * jj + 1) * 512 + ((slotv ^ (2 * jj + 1)) << 4) + lowv);
      vf.u[jj] = lo | (hi << 16);
    }
#pragma unroll
    for (int tt = 0; tt < 2; ++tt) {
      // B-frag needs keys 16ks + 8hl + 0..7.
      // hl=0 lane: own pi base+0,1 then partner(hl=1)'s pi base+0,1;
      // hl=1 lane: partner(hl=0)'s pi base+2,3 then own pi base+2,3.
      // => hl=0 SENDS pi base+2,3; hl=1 SENDS pi base+0,1. (round-3 bug: send
      //    selection was inverted — each lane sent the piece it meant to keep)
      const int base = 4 * (ks & 1);
      const unsigned o0 = pkv[at][tt][base + 0];
      const unsigned o1 = pkv[at][tt][base + 1];
      const unsigned o2 = pkv[at][tt][base + 2];
      const unsigned o3 = pkv[at][tt][base + 3];
      const unsigned s0 = hl ? o0 : o2;
      const unsigned s1 = hl ? o1 : o3;
      const unsigned y0 = __shfl_xor(s0, 32);
      const unsigned y1 = __shfl_xor(s1, 32);
      FragU pf;
      pf.u[0] = hl ? y0 : o0;
      pf.u[1] = hl ? y1 : o1;
      pf.u[2] = hl ? o2 : y0;
      pf.u[3] = hl ? o3 : y1;
      oac[tt] = __builtin_amdgcn_mfma_f32_32x32x16_bf16(vf.s, pf.s, oac[tt], 0, 0, 0);
    }
  }

  // ---- store O^T -> wout[tok][128] bf16 (w already folded via inv)
#pragma unroll
  for (int tt = 0; tt < 2; ++tt) {
    ushort* wr = wout + ((bh + (size_t)k * 64 + 32 * tt + c) << 7) + h * 32 + 4 * hl;
#pragma unroll
    for (int pi = 0; pi < 4; ++pi) {
      uint2 pkw;
      pkw.x = pack2bf(oac[tt][4 * pi + 0], oac[tt][4 * pi + 1]);
      pkw.y = pack2bf(oac[tt][4 * pi + 2], oac[tt][4 * pi + 3]);
      *(uint2*)(wr + pi * 8) = pkw;
    }
  }
}

// ---------------------------------------------------------------------------
// Kernel 3: gather-based finalize (CSR walk), bf16 v + bf16 wout inputs.
// ---------------------------------------------------------------------------
__global__ __launch_bounds__(256) void final_gather(
    const ushort* __restrict__ qkvb, const ushort* __restrict__ wout,
    const float* __restrict__ sims, const int* __restrict__ cnt,
    const int* __restrict__ offs, const int* __restrict__ list,
    float* __restrict__ out) {
  __shared__ __align__(16) float res[64][132];
  __shared__ float invd[64];
  __shared__ int cnt_s[64], st_s[64];
  const int t = threadIdx.x;
  const int pos0 = blockIdx.x * 64;
  const int b = blockIdx.y;
  const size_t bh = (size_t)b << 14;

  if (t < 64) {
    const int p = pos0 + t;
    const int c = cnt[bh + p];
    cnt_s[t] = c;
    st_s[t] = offs[bh + p] - c;
  }
  // load v rows (qkv channels 128..255, bf16) into res
#pragma unroll
  for (int it = 0; it < 8; ++it) {
    const int f = t + it * 256;
    const int row = f >> 5;
    const int c4 = (f & 31) * 4;
    const uint2 v = *(const uint2*)&qkvb[(bh + pos0 + row) * 256 + 128 + c4];
    res[row][c4 + 0] = bflo(v.x);
    res[row][c4 + 1] = bfhi(v.x);
    res[row][c4 + 2] = bflo(v.y);
    res[row][c4 + 3] = bfhi(v.y);
  }
  __syncthreads();

  if (t < 64) {
    float s = 0.f;
    const int n = cnt_s[t], st = st_s[t];
    for (int j = 0; j < n; ++j) {
      const int tok = list[bh + st + j];
      s += sims[bh + tok];
    }
    invd[t] = 1.0f / (1.0f + s);
  }
  __syncthreads();

  {
    const int w = t >> 6, l = t & 63;
    for (int p16 = 0; p16 < 16; ++p16) {
      const int p = w * 16 + p16;
      const int n = cnt_s[p], st = st_s[p];
      if (n) {
        float2 a = *(float2*)&res[p][l * 2];
        for (int j = 0; j < n; ++j) {
          const int tok = list[bh + st + j];
          const unsigned u = ((const unsigned*)(wout + ((bh + tok) << 7)))[l];
          a.x += bflo(u);
          a.y += bfhi(u);
        }
        res[p][l * 2] = a.x;
        res[p][l * 2 + 1] = a.y;
      }
    }
  }
  __syncthreads();

  {
    const int px = t & 63;
    const int cg = t >> 6;
    const float inv = invd[px];
#pragma unroll
    for (int it = 0; it < 32; ++it) {
      const int c = cg * 32 + it;
      out[(bh << 7) + (size_t)c * NHW + pos0 + px] = res[px][c] * inv;
    }
  }
}

// ---------------------------------------------------------------------------
extern "C" void kernel_launch(void* const* d_in, const int* in_sizes, int n_in,
                              void* d_out, int out_size, void* d_ws, size_t ws_size,
                              hipStream_t stream) {
  (void)in_sizes; (void)n_in; (void)out_size; (void)ws_size;
  const float* x     = (const float*)d_in[0];
  const float* jp    = (const float*)d_in[1];
  const float* sims  = (const float*)d_in[2];
  const float* gamma = (const float*)d_in[3];
  const float* beta  = (const float*)d_in[4];
  const float* Wq    = (const float*)d_in[5];
  const float* Wk    = (const float*)d_in[6];
  const float* Wv    = (const float*)d_in[7];
  const int* indices = (const int*)d_in[8];
  float* out = (float*)d_out;

  char* ws = (char*)d_ws;
  ushort* qkvb = (ushort*)ws;                       // [B][HW][256] bf16  67.1MB
  ushort* wout = (ushort*)(ws + 67108864);          // [B][HW][128] bf16  33.5MB
  float*  WT   = (float*)(ws + 100663296);          // [128][256] f32
  int*    cnt  = (int*)(ws + 100794368);            // [B][HW]
  int*    offs = (int*)(ws + 101318656);            // [B][HW]
  int*    list = (int*)(ws + 101842944);            // [B][HW]

  zero_cnt_kernel<<<dim3(512), 256, 0, stream>>>(cnt);
  count_kernel<<<dim3(512), 256, 0, stream>>>(indices, cnt);
  wt_kernel<<<dim3(NC), 256, 0, stream>>>(Wq, Wk, Wv, WT);
  ln_proj_kernel<<<dim3(NHW / 64, NB), 256, 0, stream>>>(x, gamma, beta, WT, qkvb);
  scan_kernel<<<dim3(NB), 256, 0, stream>>>(cnt, offs);
  fill_kernel<<<dim3(512), 256, 0, stream>>>(indices, offs, list);
  attn_kernel<<<dim3(NK, NB), 256, 0, stream>>>(qkvb, indices, sims, jp, wout);
  final_gather<<<dim3(NHW / 64, NB), 256, 0, stream>>>(qkvb, wout, sims, cnt,
                                                       offs, list, out);
}

// Round 5
// 254.672 us; speedup vs baseline: 4.6696x; 1.3570x over previous
//
#include <hip/hip_runtime.h>
#include <hip/hip_bf16.h>
#include <math.h>

#define NB 8
#define NC 128
#define NHW 16384
#define NK 256
#define NT 64
#define SCALE_F 0.25f
#define LN_EPS 1e-6f

typedef short s16x8 __attribute__((ext_vector_type(8)));
typedef float f32x16 __attribute__((ext_vector_type(16)));

union FragU { unsigned u[4]; s16x8 s; };

static __device__ inline unsigned pack2bf(float a, float b) {
  union { __hip_bfloat162 h; unsigned u; } x;
  x.h = __float22bfloat162_rn(make_float2(a, b));
  return x.u;
}
static __device__ inline float bflo(unsigned u) { return __uint_as_float(u << 16); }
static __device__ inline float bfhi(unsigned u) { return __uint_as_float(u & 0xffff0000u); }

// ---------------------------------------------------------------------------
// Kernel 0: pack Wq/Wk/Wv into bf16 Wb[d][c], d: 0..63 q | 64..127 k | 128..255 v
// (d-major, c contiguous -> MFMA A-frag = one 16B load)
// ---------------------------------------------------------------------------
__global__ __launch_bounds__(256) void wb_kernel(const float* __restrict__ Wq,
                                                 const float* __restrict__ Wk,
                                                 const float* __restrict__ Wv,
                                                 ushort* __restrict__ Wb) {
  const int t = threadIdx.x;
  const int d = blockIdx.x * 2 + (t >> 7);
  const int c = t & 127;
  float v;
  if (d < 64)       v = Wq[d * NC + c];
  else if (d < 128) v = Wk[(d - 64) * NC + c];
  else              v = Wv[(d - 128) * NC + c];
  Wb[d * NC + c] = (ushort)(pack2bf(v, 0.f) & 0xffffu);
}

// ---------------------------------------------------------------------------
// index-inversion helpers: cnt -> scan -> fill (CSR per batch)
// ---------------------------------------------------------------------------
__global__ __launch_bounds__(256) void zero_cnt_kernel(int* __restrict__ cnt) {
  cnt[blockIdx.x * 256 + threadIdx.x] = 0;
}

__global__ __launch_bounds__(256) void count_kernel(const int* __restrict__ indices,
                                                    int* __restrict__ cnt) {
  const int g = blockIdx.x * 256 + threadIdx.x;
  const int b = g >> 14;
  atomicAdd(&cnt[(b << 14) + indices[g]], 1);
}

__global__ __launch_bounds__(256) void scan_kernel(const int* __restrict__ cnt,
                                                   int* __restrict__ offs) {
  const int b = blockIdx.x, t = threadIdx.x;
  const int base = (b << 14) + t * 64;
  int s = 0;
  for (int j = 0; j < 64; ++j) s += cnt[base + j];
  __shared__ int sums[256];
  sums[t] = s;
  __syncthreads();
  for (int off = 1; off < 256; off <<= 1) {
    int v = (t >= off) ? sums[t - off] : 0;
    __syncthreads();
    sums[t] += v;
    __syncthreads();
  }
  int run = (t == 0) ? 0 : sums[t - 1];
  for (int j = 0; j < 64; ++j) {
    offs[base + j] = run;
    run += cnt[base + j];
  }
}

__global__ __launch_bounds__(256) void fill_kernel(const int* __restrict__ indices,
                                                   int* __restrict__ offs,
                                                   int* __restrict__ list) {
  const int g = blockIdx.x * 256 + threadIdx.x;
  const int b = g >> 14;
  const int tok = g & 16383;
  const int pos = indices[g];
  const int slot = atomicAdd(&offs[(b << 14) + pos], 1);
  list[(b << 14) + slot] = tok;
}

// ---------------------------------------------------------------------------
// Kernel 1: fused LayerNorm + MFMA QKV projection.
// Block = 64 positions; thread (p = t&63, q = t>>6) holds x[q*32..+31][p] in regs.
// LN stats via LDS cross-wave combine; xn packed bf16 to LDS [p][c] with
// 16B-slot XOR swizzle (slot ^= p&15, both sides). Wave w computes d-range
// [64w, 64w+64) x 64 pos via mfma_f32_32x32x16_bf16; D[d][pos] stores straight
// into token-major qkvb.
// ---------------------------------------------------------------------------
__global__ __launch_bounds__(256) void ln_proj_kernel(
    const float* __restrict__ x, const float* __restrict__ gamma,
    const float* __restrict__ beta, const ushort* __restrict__ Wb,
    ushort* __restrict__ qkvb) {
  __shared__ __align__(16) ushort xn[64 * 128];  // 16 KB, swizzled
  __shared__ float stats[2][4][64];
  const int t = threadIdx.x;
  const int b = blockIdx.y;
  const int pos0 = blockIdx.x * 64;
  const int p = t & 63;
  const int q = t >> 6;

  // ---- load 32 channels of position p (coalesced: 64 lanes = consecutive p)
  float xr[32];
  {
    const float* xb = x + ((size_t)b * NC + q * 32) * NHW + pos0 + p;
#pragma unroll
    for (int j = 0; j < 32; ++j) xr[j] = xb[(size_t)j * NHW];
  }
  float s = 0.f, ss = 0.f;
#pragma unroll
  for (int j = 0; j < 32; ++j) { s += xr[j]; ss = fmaf(xr[j], xr[j], ss); }
  stats[0][q][p] = s;
  stats[1][q][p] = ss;
  __syncthreads();
  const float S  = stats[0][0][p] + stats[0][1][p] + stats[0][2][p] + stats[0][3][p];
  const float SS = stats[1][0][p] + stats[1][1][p] + stats[1][2][p] + stats[1][3][p];
  const float mu = S * (1.0f / 128.0f);
  const float rstd = rsqrtf(SS * (1.0f / 128.0f) - mu * mu + LN_EPS);

  // ---- normalize + gamma/beta (wave-uniform scalar loads), pack bf16 to LDS
#pragma unroll
  for (int sl = 0; sl < 4; ++sl) {
    uint4 pk;
    unsigned* pw = (unsigned*)&pk;
#pragma unroll
    for (int e = 0; e < 4; ++e) {
      const int j = sl * 8 + e * 2;
      const int c0 = q * 32 + j;
      const float a  = gamma[c0]     * ((xr[j]     - mu) * rstd) + beta[c0];
      const float bb = gamma[c0 + 1] * ((xr[j + 1] - mu) * rstd) + beta[c0 + 1];
      pw[e] = pack2bf(a, bb);
    }
    const int slot = (q * 4 + sl) ^ (p & 15);
    *(uint4*)((char*)xn + p * 256 + slot * 16) = pk;
  }
  __syncthreads();

  // ---- MFMA: wave q owns d-tiles {2q, 2q+1} (64 d), pos-tiles {0,1}
  const int l = t & 63;
  const int cl = l & 31;
  const int hl = l >> 5;

  s16x8 af[2][8];
#pragma unroll
  for (int dt = 0; dt < 2; ++dt) {
    const int d = 64 * q + 32 * dt + cl;
#pragma unroll
    for (int ks = 0; ks < 8; ++ks)
      af[dt][ks] = *(const s16x8*)(Wb + d * NC + ks * 16 + 8 * hl);
  }

  f32x16 acc[2][2];
#pragma unroll
  for (int dt = 0; dt < 2; ++dt)
#pragma unroll
    for (int pt = 0; pt < 2; ++pt)
#pragma unroll
      for (int i = 0; i < 16; ++i) acc[dt][pt][i] = 0.f;

#pragma unroll
  for (int pt = 0; pt < 2; ++pt) {
    const int row = 32 * pt + cl;  // pos within tile (B-frag col = cl)
#pragma unroll
    for (int ks = 0; ks < 8; ++ks) {
      const int slot = (2 * ks + hl) ^ (row & 15);
      const s16x8 bf = *(const s16x8*)((const char*)xn + row * 256 + slot * 16);
      acc[0][pt] = __builtin_amdgcn_mfma_f32_32x32x16_bf16(af[0][ks], bf, acc[0][pt], 0, 0, 0);
      acc[1][pt] = __builtin_amdgcn_mfma_f32_32x32x16_bf16(af[1][ks], bf, acc[1][pt], 0, 0, 0);
    }
  }

  // ---- store D[d][pos] -> qkvb[pos][d] (4 contiguous d per reg-quad)
#pragma unroll
  for (int dt = 0; dt < 2; ++dt)
#pragma unroll
    for (int pt = 0; pt < 2; ++pt) {
      ushort* wr = qkvb + ((size_t)b * NHW + pos0 + 32 * pt + cl) * 256 +
                   64 * q + 32 * dt + 4 * hl;
#pragma unroll
      for (int r4 = 0; r4 < 4; ++r4) {
        uint2 pkw;
        pkw.x = pack2bf(acc[dt][pt][4 * r4 + 0], acc[dt][pt][4 * r4 + 1]);
        pkw.y = pack2bf(acc[dt][pt][4 * r4 + 2], acc[dt][pt][4 * r4 + 3]);
        *(uint2*)(wr + r4 * 8) = pkw;
      }
    }
}

// ---------------------------------------------------------------------------
// Kernel 2: MFMA attention. Block = (b,k); wave = head h.
// S^T = mfma(K, Q^T) [swapped -> softmax keys land in-lane]; P repacked in-reg;
// O^T = mfma(V^T, P^T); dense bf16 store of w*out.
// LDS: kqv[64 tok][256 ch] bf16, 16B-slot XOR swizzle: slot ^= (row&7).
// ---------------------------------------------------------------------------
__global__ __launch_bounds__(256) void attn_kernel(
    const ushort* __restrict__ qkvb, const int* __restrict__ indices,
    const float* __restrict__ sims, const float* __restrict__ jp,
    ushort* __restrict__ wout) {
  __shared__ __align__(16) ushort kqv[64 * 256];
  __shared__ int idx_s[NT];
  __shared__ float w_s[NT];
  const int t = threadIdx.x;
  const int k = blockIdx.x;
  const int b = blockIdx.y;
  const size_t bh = (size_t)b << 14;

  if (t < NT) {
    const int g = (b * NK + k) * NT + t;
    idx_s[t] = indices[g];
    w_s[t] = sims[g];
  }
  const float sp = SCALE_F * jp[b * NK + k];
  __syncthreads();

  // ---- gather: one wave copies one token row (512B) per iter, swizzled into LDS
  {
    const int w = t >> 6, l = t & 63;
    const int c4 = l * 4;
    const int slot = c4 >> 3;
    const int lowb = (c4 & 7) * 2;
#pragma unroll
    for (int it = 0; it < 16; ++it) {
      const int tok = w * 16 + it;
      const uint2 v = *(const uint2*)&qkvb[(bh + idx_s[tok]) * 256 + c4];
      *(uint2*)((char*)kqv + tok * 512 + ((slot ^ (tok & 7)) << 4) + lowb) = v;
    }
  }
  __syncthreads();

  const int h = t >> 6;
  const int l = t & 63;
  const int c = l & 31;   // MFMA column (tok for S^T, ch for O^T)
  const int hl = l >> 5;

  // ---- Q/K fragments (A/B-frag layout: row/col = l&31, k = 8*(l>>5)+j)
  s16x8 qf[2], kf[2];
  {
    const int slotq = h * 2 + hl;
    const int slotk = 8 + h * 2 + hl;
#pragma unroll
    for (int tt = 0; tt < 2; ++tt) {
      const int row = 32 * tt + c;
      qf[tt] = *(const s16x8*)((const char*)kqv + row * 512 + ((slotq ^ (row & 7)) << 4));
    }
#pragma unroll
    for (int at = 0; at < 2; ++at) {
      const int row = 32 * at + c;
      kf[at] = *(const s16x8*)((const char*)kqv + row * 512 + ((slotk ^ (row & 7)) << 4));
    }
  }

  // ---- QK^T (swapped): sacc[at][tt] = S^T tile [key=32at+R(reg,hl)][tok=32tt+c]
  f32x16 sacc[2][2];
#pragma unroll
  for (int at = 0; at < 2; ++at)
#pragma unroll
    for (int tt = 0; tt < 2; ++tt) {
#pragma unroll
      for (int i = 0; i < 16; ++i) sacc[at][tt][i] = 0.f;
      sacc[at][tt] = __builtin_amdgcn_mfma_f32_32x32x16_bf16(kf[at], qf[tt], sacc[at][tt], 0, 0, 0);
    }

  // ---- softmax over keys (32 in-lane + xor32), fold sims weight into P
  // pkv[at][tt][pi] (for this hl) = keys 32*at + 8*(pi>>1) + 4*hl + 2*(pi&1) + {0,1}
  unsigned pkv[2][2][8];
#pragma unroll
  for (int tt = 0; tt < 2; ++tt) {
    float m = -1e30f;
#pragma unroll
    for (int at = 0; at < 2; ++at)
#pragma unroll
      for (int i = 0; i < 16; ++i) m = fmaxf(m, sacc[at][tt][i]);
    m = fmaxf(m, __shfl_xor(m, 32));
    float sum = 0.f;
#pragma unroll
    for (int at = 0; at < 2; ++at)
#pragma unroll
      for (int i = 0; i < 16; ++i) {
        const float e = __expf((sacc[at][tt][i] - m) * sp);
        sacc[at][tt][i] = e;
        sum += e;
      }
    sum += __shfl_xor(sum, 32);
    const float inv = w_s[32 * tt + c] / sum;
#pragma unroll
    for (int at = 0; at < 2; ++at)
#pragma unroll
      for (int pi = 0; pi < 8; ++pi)
        pkv[at][tt][pi] = pack2bf(sacc[at][tt][2 * pi] * inv, sacc[at][tt][2 * pi + 1] * inv);
  }

  // ---- PV: oac[tt] = O^T tile [ch'=R(reg,hl)][tok=32tt+c]
  f32x16 oac[2];
#pragma unroll
  for (int tt = 0; tt < 2; ++tt)
#pragma unroll
    for (int i = 0; i < 16; ++i) oac[tt][i] = 0.f;

  const int slotv = 16 + h * 4 + (c >> 3);
  const int lowv = (c & 7) * 2;
#pragma unroll
  for (int ks = 0; ks < 4; ++ks) {
    const int at = ks >> 1;
    const int ksb = 16 * ks + 8 * hl;
    // V^T A-frag: elem j = V[key=ksb+j][h*32+c]; (ksb+j)&7 == j so swizzle XOR = j
    FragU vf;
#pragma unroll
    for (int jj = 0; jj < 4; ++jj) {
      const unsigned lo =
          *(const ushort*)((const char*)kqv + (ksb + 2 * jj) * 512 + ((slotv ^ (2 * jj)) << 4) + lowv);
      const unsigned hi =
          *(const ushort*)((const char*)kqv + (ksb + 2 * jj + 1) * 512 + ((slotv ^ (2 * jj + 1)) << 4) + lowv);
      vf.u[jj] = lo | (hi << 16);
    }
#pragma unroll
    for (int tt = 0; tt < 2; ++tt) {
      // B-frag needs keys 16ks + 8hl + 0..7.
      // hl=0 keeps own pi base+0,1 and receives partner's base+0,1;
      // hl=1 keeps own pi base+2,3 and receives partner's base+2,3.
      // => hl=0 SENDS pi base+2,3; hl=1 SENDS pi base+0,1.
      const int base = 4 * (ks & 1);
      const unsigned o0 = pkv[at][tt][base + 0];
      const unsigned o1 = pkv[at][tt][base + 1];
      const unsigned o2 = pkv[at][tt][base + 2];
      const unsigned o3 = pkv[at][tt][base + 3];
      const unsigned s0 = hl ? o0 : o2;
      const unsigned s1 = hl ? o1 : o3;
      const unsigned y0 = __shfl_xor(s0, 32);
      const unsigned y1 = __shfl_xor(s1, 32);
      FragU pf;
      pf.u[0] = hl ? y0 : o0;
      pf.u[1] = hl ? y1 : o1;
      pf.u[2] = hl ? o2 : y0;
      pf.u[3] = hl ? o3 : y1;
      oac[tt] = __builtin_amdgcn_mfma_f32_32x32x16_bf16(vf.s, pf.s, oac[tt], 0, 0, 0);
    }
  }

  // ---- store O^T -> wout[tok][128] bf16 (w already folded via inv)
#pragma unroll
  for (int tt = 0; tt < 2; ++tt) {
    ushort* wr = wout + ((bh + (size_t)k * 64 + 32 * tt + c) << 7) + h * 32 + 4 * hl;
#pragma unroll
    for (int pi = 0; pi < 4; ++pi) {
      uint2 pkw;
      pkw.x = pack2bf(oac[tt][4 * pi + 0], oac[tt][4 * pi + 1]);
      pkw.y = pack2bf(oac[tt][4 * pi + 2], oac[tt][4 * pi + 3]);
      *(uint2*)(wr + pi * 8) = pkw;
    }
  }
}

// ---------------------------------------------------------------------------
// Kernel 3: gather-based finalize (CSR walk), bf16 v + bf16 wout inputs.
// ---------------------------------------------------------------------------
__global__ __launch_bounds__(256) void final_gather(
    const ushort* __restrict__ qkvb, const ushort* __restrict__ wout,
    const float* __restrict__ sims, const int* __restrict__ cnt,
    const int* __restrict__ offs, const int* __restrict__ list,
    float* __restrict__ out) {
  __shared__ __align__(16) float res[64][132];
  __shared__ float invd[64];
  __shared__ int cnt_s[64], st_s[64];
  const int t = threadIdx.x;
  const int pos0 = blockIdx.x * 64;
  const int b = blockIdx.y;
  const size_t bh = (size_t)b << 14;

  if (t < 64) {
    const int p = pos0 + t;
    const int c = cnt[bh + p];
    cnt_s[t] = c;
    st_s[t] = offs[bh + p] - c;
  }
  // load v rows (qkv channels 128..255, bf16) into res
#pragma unroll
  for (int it = 0; it < 8; ++it) {
    const int f = t + it * 256;
    const int row = f >> 5;
    const int c4 = (f & 31) * 4;
    const uint2 v = *(const uint2*)&qkvb[(bh + pos0 + row) * 256 + 128 + c4];
    res[row][c4 + 0] = bflo(v.x);
    res[row][c4 + 1] = bfhi(v.x);
    res[row][c4 + 2] = bflo(v.y);
    res[row][c4 + 3] = bfhi(v.y);
  }
  __syncthreads();

  if (t < 64) {
    float s = 0.f;
    const int n = cnt_s[t], st = st_s[t];
    for (int j = 0; j < n; ++j) {
      const int tok = list[bh + st + j];
      s += sims[bh + tok];
    }
    invd[t] = 1.0f / (1.0f + s);
  }
  __syncthreads();

  {
    const int w = t >> 6, l = t & 63;
    for (int p16 = 0; p16 < 16; ++p16) {
      const int p = w * 16 + p16;
      const int n = cnt_s[p], st = st_s[p];
      if (n) {
        float2 a = *(float2*)&res[p][l * 2];
        for (int j = 0; j < n; ++j) {
          const int tok = list[bh + st + j];
          const unsigned u = ((const unsigned*)(wout + ((bh + tok) << 7)))[l];
          a.x += bflo(u);
          a.y += bfhi(u);
        }
        res[p][l * 2] = a.x;
        res[p][l * 2 + 1] = a.y;
      }
    }
  }
  __syncthreads();

  {
    const int px = t & 63;
    const int cg = t >> 6;
    const float inv = invd[px];
#pragma unroll
    for (int it = 0; it < 32; ++it) {
      const int c = cg * 32 + it;
      out[(bh << 7) + (size_t)c * NHW + pos0 + px] = res[px][c] * inv;
    }
  }
}

// ---------------------------------------------------------------------------
extern "C" void kernel_launch(void* const* d_in, const int* in_sizes, int n_in,
                              void* d_out, int out_size, void* d_ws, size_t ws_size,
                              hipStream_t stream) {
  (void)in_sizes; (void)n_in; (void)out_size; (void)ws_size;
  const float* x     = (const float*)d_in[0];
  const float* jp    = (const float*)d_in[1];
  const float* sims  = (const float*)d_in[2];
  const float* gamma = (const float*)d_in[3];
  const float* beta  = (const float*)d_in[4];
  const float* Wq    = (const float*)d_in[5];
  const float* Wk    = (const float*)d_in[6];
  const float* Wv    = (const float*)d_in[7];
  const int* indices = (const int*)d_in[8];
  float* out = (float*)d_out;

  char* ws = (char*)d_ws;
  ushort* qkvb = (ushort*)ws;                       // [B][HW][256] bf16  67.1MB
  ushort* wout = (ushort*)(ws + 67108864);          // [B][HW][128] bf16  33.5MB
  ushort* Wb   = (ushort*)(ws + 100663296);         // [256][128] bf16    64KB
  int*    cnt  = (int*)(ws + 100728832);            // [B][HW]
  int*    offs = (int*)(ws + 101253120);            // [B][HW]
  int*    list = (int*)(ws + 101777408);            // [B][HW]

  zero_cnt_kernel<<<dim3(512), 256, 0, stream>>>(cnt);
  count_kernel<<<dim3(512), 256, 0, stream>>>(indices, cnt);
  wb_kernel<<<dim3(128), 256, 0, stream>>>(Wq, Wk, Wv, Wb);
  ln_proj_kernel<<<dim3(NHW / 64, NB), 256, 0, stream>>>(x, gamma, beta, Wb, qkvb);
  scan_kernel<<<dim3(NB), 256, 0, stream>>>(cnt, offs);
  fill_kernel<<<dim3(512), 256, 0, stream>>>(indices, offs, list);
  attn_kernel<<<dim3(NK, NB), 256, 0, stream>>>(qkvb, indices, sims, jp, wout);
  final_gather<<<dim3(NHW / 64, NB), 256, 0, stream>>>(qkvb, wout, sims, cnt,
                                                       offs, list, out);
}

// Round 6
// 239.276 us; speedup vs baseline: 4.9700x; 1.0643x over previous
//
#include <hip/hip_runtime.h>
#include <hip/hip_bf16.h>
#include <math.h>

#define NB 8
#define NC 128
#define NHW 16384
#define NK 256
#define NT 64
#define SCALE_F 0.25f
#define LN_EPS 1e-6f

typedef short s16x8 __attribute__((ext_vector_type(8)));
typedef float f32x16 __attribute__((ext_vector_type(16)));

union FragU { unsigned u[4]; s16x8 s; };

static __device__ inline unsigned pack2bf(float a, float b) {
  union { __hip_bfloat162 h; unsigned u; } x;
  x.h = __float22bfloat162_rn(make_float2(a, b));
  return x.u;
}
static __device__ inline float bflo(unsigned u) { return __uint_as_float(u << 16); }
static __device__ inline float bfhi(unsigned u) { return __uint_as_float(u & 0xffff0000u); }

// XCD-aware block swizzle for 256-block grids (8 XCDs x 32 contiguous blocks):
// consecutive pos-blocks land on the SAME XCD -> 8KB-contiguous per-channel
// segments in one L2 instead of 256B shreds round-robined across 8 L2s.
static __device__ inline int xcd_swz(int bx) { return ((bx & 7) << 5) | (bx >> 3); }

// ---------------------------------------------------------------------------
// Kernel 0: pack Wq/Wk/Wv into bf16 Wb[d][c], d: 0..63 q | 64..127 k | 128..255 v
// ---------------------------------------------------------------------------
__global__ __launch_bounds__(256) void wb_kernel(const float* __restrict__ Wq,
                                                 const float* __restrict__ Wk,
                                                 const float* __restrict__ Wv,
                                                 ushort* __restrict__ Wb) {
  const int t = threadIdx.x;
  const int d = blockIdx.x * 2 + (t >> 7);
  const int c = t & 127;
  float v;
  if (d < 64)       v = Wq[d * NC + c];
  else if (d < 128) v = Wk[(d - 64) * NC + c];
  else              v = Wv[(d - 128) * NC + c];
  Wb[d * NC + c] = (ushort)(pack2bf(v, 0.f) & 0xffffu);
}

// ---------------------------------------------------------------------------
// index-inversion helpers: cnt -> scan -> fill (CSR per batch)
// ---------------------------------------------------------------------------
__global__ __launch_bounds__(256) void zero_cnt_kernel(int* __restrict__ cnt) {
  cnt[blockIdx.x * 256 + threadIdx.x] = 0;
}

__global__ __launch_bounds__(256) void count_kernel(const int* __restrict__ indices,
                                                    int* __restrict__ cnt) {
  const int g = blockIdx.x * 256 + threadIdx.x;
  const int b = g >> 14;
  atomicAdd(&cnt[(b << 14) + indices[g]], 1);
}

__global__ __launch_bounds__(256) void scan_kernel(const int* __restrict__ cnt,
                                                   int* __restrict__ offs) {
  const int b = blockIdx.x, t = threadIdx.x;
  const int base = (b << 14) + t * 64;
  int s = 0;
  for (int j = 0; j < 64; ++j) s += cnt[base + j];
  __shared__ int sums[256];
  sums[t] = s;
  __syncthreads();
  for (int off = 1; off < 256; off <<= 1) {
    int v = (t >= off) ? sums[t - off] : 0;
    __syncthreads();
    sums[t] += v;
    __syncthreads();
  }
  int run = (t == 0) ? 0 : sums[t - 1];
  for (int j = 0; j < 64; ++j) {
    offs[base + j] = run;
    run += cnt[base + j];
  }
}

__global__ __launch_bounds__(256) void fill_kernel(const int* __restrict__ indices,
                                                   int* __restrict__ offs,
                                                   int* __restrict__ list) {
  const int g = blockIdx.x * 256 + threadIdx.x;
  const int b = g >> 14;
  const int tok = g & 16383;
  const int pos = indices[g];
  const int slot = atomicAdd(&offs[(b << 14) + pos], 1);
  list[(b << 14) + slot] = tok;
}

// ---------------------------------------------------------------------------
// Kernel 1: fused LayerNorm + MFMA QKV projection.
// Block = 64 positions. Thread (c16 = t&15 -> positions c16*4..+3,
// cg = t>>4 -> channels cg*8..+7) loads x as float4 (1KB/wave-instr).
// LN stats: shfl_xor(16,32) + 4-wave LDS combine. xn bf16 in LDS [pos][ch]
// with 16B-slot swizzle (slot ^= pos&15). MFMA D[d][pos] goes to a swizzled
// 32KB LDS tile (overlaying xn), then stores are fully-coalesced 512B rows.
// ---------------------------------------------------------------------------
__global__ __launch_bounds__(256) void ln_proj_kernel(
    const float* __restrict__ x, const float* __restrict__ gamma,
    const float* __restrict__ beta, const ushort* __restrict__ Wb,
    ushort* __restrict__ qkvb) {
  __shared__ __align__(16) ushort qbuf[64 * 256];  // 32 KB; first 16 KB = xn
  __shared__ __align__(16) float stats_s[2][4][64];
  const int t = threadIdx.x;
  const int b = blockIdx.y;
  const int pos0 = xcd_swz(blockIdx.x) * 64;
  const int c16 = t & 15;   // position quad: p = c16*4 + pp
  const int cg = t >> 4;    // channel group: c = cg*8 + j

  // ---- load 8 channels x 4 positions as float4
  float4 xv[8];
  {
    const float* xb = x + ((size_t)b * NC + cg * 8) * NHW + pos0 + c16 * 4;
#pragma unroll
    for (int j = 0; j < 8; ++j) xv[j] = *(const float4*)(xb + (size_t)j * NHW);
  }

  // ---- LN stats: per-position partial sums over 8 channels
  float s[4], ss[4];
#pragma unroll
  for (int pp = 0; pp < 4; ++pp) { s[pp] = 0.f; ss[pp] = 0.f; }
#pragma unroll
  for (int j = 0; j < 8; ++j) {
    const float* f = (const float*)&xv[j];
#pragma unroll
    for (int pp = 0; pp < 4; ++pp) { s[pp] += f[pp]; ss[pp] = fmaf(f[pp], f[pp], ss[pp]); }
  }
#pragma unroll
  for (int pp = 0; pp < 4; ++pp) {
    s[pp] += __shfl_xor(s[pp], 16);  ss[pp] += __shfl_xor(ss[pp], 16);
    s[pp] += __shfl_xor(s[pp], 32);  ss[pp] += __shfl_xor(ss[pp], 32);
  }
  const int w = t >> 6;
  if ((cg & 3) == 0) {
    *(float4*)&stats_s[0][w][c16 * 4] = make_float4(s[0], s[1], s[2], s[3]);
    *(float4*)&stats_s[1][w][c16 * 4] = make_float4(ss[0], ss[1], ss[2], ss[3]);
  }
  __syncthreads();
  float4 S = *(float4*)&stats_s[0][0][c16 * 4];
  float4 SS = *(float4*)&stats_s[1][0][c16 * 4];
#pragma unroll
  for (int ww = 1; ww < 4; ++ww) {
    const float4 a = *(float4*)&stats_s[0][ww][c16 * 4];
    const float4 bb = *(float4*)&stats_s[1][ww][c16 * 4];
    S.x += a.x; S.y += a.y; S.z += a.z; S.w += a.w;
    SS.x += bb.x; SS.y += bb.y; SS.z += bb.z; SS.w += bb.w;
  }
  float mu[4], rstd[4];
  {
    const float* Sp = (const float*)&S;
    const float* SSp = (const float*)&SS;
#pragma unroll
    for (int pp = 0; pp < 4; ++pp) {
      mu[pp] = Sp[pp] * (1.0f / 128.0f);
      rstd[pp] = rsqrtf(SSp[pp] * (1.0f / 128.0f) - mu[pp] * mu[pp] + LN_EPS);
    }
  }

  // ---- normalize + affine, pack bf16 into xn (swizzled 16B slots)
  {
    float g[8], be[8];
#pragma unroll
    for (int j = 0; j < 8; ++j) { g[j] = gamma[cg * 8 + j]; be[j] = beta[cg * 8 + j]; }
#pragma unroll
    for (int pp = 0; pp < 4; ++pp) {
      const int p_loc = c16 * 4 + pp;
      uint4 pk;
      unsigned* pw = (unsigned*)&pk;
#pragma unroll
      for (int e = 0; e < 4; ++e) {
        const float* f0 = (const float*)&xv[2 * e];
        const float* f1 = (const float*)&xv[2 * e + 1];
        const float a0 = g[2 * e] * ((f0[pp] - mu[pp]) * rstd[pp]) + be[2 * e];
        const float a1 = g[2 * e + 1] * ((f1[pp] - mu[pp]) * rstd[pp]) + be[2 * e + 1];
        pw[e] = pack2bf(a0, a1);
      }
      const int slot = cg ^ (p_loc & 15);
      *(uint4*)((char*)qbuf + p_loc * 256 + slot * 16) = pk;
    }
  }
  __syncthreads();

  // ---- MFMA: wave w owns d-tiles {2w, 2w+1} (64 d), pos-tiles {0,1}
  const int l = t & 63;
  const int cl = l & 31;
  const int hl = l >> 5;

  s16x8 af[2][8];
#pragma unroll
  for (int dt = 0; dt < 2; ++dt) {
    const int d = 64 * w + 32 * dt + cl;
#pragma unroll
    for (int ks = 0; ks < 8; ++ks)
      af[dt][ks] = *(const s16x8*)(Wb + d * NC + ks * 16 + 8 * hl);
  }

  f32x16 acc[2][2];
#pragma unroll
  for (int dt = 0; dt < 2; ++dt)
#pragma unroll
    for (int pt = 0; pt < 2; ++pt)
#pragma unroll
      for (int i = 0; i < 16; ++i) acc[dt][pt][i] = 0.f;

#pragma unroll
  for (int pt = 0; pt < 2; ++pt) {
    const int row = 32 * pt + cl;
#pragma unroll
    for (int ks = 0; ks < 8; ++ks) {
      const int slot = (2 * ks + hl) ^ (row & 15);
      const s16x8 bf = *(const s16x8*)((const char*)qbuf + row * 256 + slot * 16);
      acc[0][pt] = __builtin_amdgcn_mfma_f32_32x32x16_bf16(af[0][ks], bf, acc[0][pt], 0, 0, 0);
      acc[1][pt] = __builtin_amdgcn_mfma_f32_32x32x16_bf16(af[1][ks], bf, acc[1][pt], 0, 0, 0);
    }
  }
  __syncthreads();  // all xn reads done before qbuf is overwritten as qout

  // ---- pack acc -> qout[pos][256ch] bf16, swizzled 16B slots (slot ^= pos&31)
#pragma unroll
  for (int dt = 0; dt < 2; ++dt)
#pragma unroll
    for (int pt = 0; pt < 2; ++pt) {
      const int pos = 32 * pt + cl;
#pragma unroll
      for (int r4 = 0; r4 < 4; ++r4) {
        const int slot16 = 8 * w + 4 * dt + r4;
        uint2 pkw;
        pkw.x = pack2bf(acc[dt][pt][4 * r4 + 0], acc[dt][pt][4 * r4 + 1]);
        pkw.y = pack2bf(acc[dt][pt][4 * r4 + 2], acc[dt][pt][4 * r4 + 3]);
        *(uint2*)((char*)qbuf + pos * 512 + ((slot16 ^ (pos & 31)) << 4) + 8 * hl) = pkw;
      }
    }
  __syncthreads();

  // ---- coalesced store: wave writes full 512B token rows
  {
    const size_t base = ((size_t)b * NHW + pos0) * 256;
#pragma unroll
    for (int it = 0; it < 16; ++it) {
      const int r = it * 4 + w;
      const uint2 v = *(const uint2*)((const char*)qbuf + r * 512 +
                                      (((l >> 1) ^ (r & 31)) << 4) + (l & 1) * 8);
      *(uint2*)(qkvb + base + r * 256 + l * 4) = v;
    }
  }
}

// ---------------------------------------------------------------------------
// Kernel 2: MFMA attention. Block = (b,k); wave = head h.
// S^T = mfma(K, Q^T) [swapped]; P repacked in-reg; O^T = mfma(V^T, P^T).
// LDS: kqv[64 tok][256 ch] bf16, 16B-slot XOR swizzle: slot ^= (row&7).
// ---------------------------------------------------------------------------
__global__ __launch_bounds__(256) void attn_kernel(
    const ushort* __restrict__ qkvb, const int* __restrict__ indices,
    const float* __restrict__ sims, const float* __restrict__ jp,
    ushort* __restrict__ wout) {
  __shared__ __align__(16) ushort kqv[64 * 256];
  __shared__ int idx_s[NT];
  __shared__ float w_s[NT];
  const int t = threadIdx.x;
  const int k = blockIdx.x;
  const int b = blockIdx.y;
  const size_t bh = (size_t)b << 14;

  if (t < NT) {
    const int g = (b * NK + k) * NT + t;
    idx_s[t] = indices[g];
    w_s[t] = sims[g];
  }
  const float sp = SCALE_F * jp[b * NK + k];
  __syncthreads();

  // ---- gather: uint4/lane, 2 token rows (1 KB) per wave-instr
  {
    const int w = t >> 6;
    const int l = t & 63;
    const int half = l >> 5;
    const int sl = l & 31;
#pragma unroll
    for (int it = 0; it < 8; ++it) {
      const int tok = w * 16 + it * 2 + half;
      const uint4 v = *(const uint4*)&qkvb[(bh + idx_s[tok]) * 256 + sl * 8];
      *(uint4*)((char*)kqv + tok * 512 + ((sl ^ (tok & 7)) << 4)) = v;
    }
  }
  __syncthreads();

  const int h = t >> 6;
  const int l = t & 63;
  const int c = l & 31;
  const int hl = l >> 5;

  // ---- Q/K fragments
  s16x8 qf[2], kf[2];
  {
    const int slotq = h * 2 + hl;
    const int slotk = 8 + h * 2 + hl;
#pragma unroll
    for (int tt = 0; tt < 2; ++tt) {
      const int row = 32 * tt + c;
      qf[tt] = *(const s16x8*)((const char*)kqv + row * 512 + ((slotq ^ (row & 7)) << 4));
    }
#pragma unroll
    for (int at = 0; at < 2; ++at) {
      const int row = 32 * at + c;
      kf[at] = *(const s16x8*)((const char*)kqv + row * 512 + ((slotk ^ (row & 7)) << 4));
    }
  }

  // ---- QK^T (swapped)
  f32x16 sacc[2][2];
#pragma unroll
  for (int at = 0; at < 2; ++at)
#pragma unroll
    for (int tt = 0; tt < 2; ++tt) {
#pragma unroll
      for (int i = 0; i < 16; ++i) sacc[at][tt][i] = 0.f;
      sacc[at][tt] = __builtin_amdgcn_mfma_f32_32x32x16_bf16(kf[at], qf[tt], sacc[at][tt], 0, 0, 0);
    }

  // ---- softmax over keys; fold sims weight into P
  unsigned pkv[2][2][8];
#pragma unroll
  for (int tt = 0; tt < 2; ++tt) {
    float m = -1e30f;
#pragma unroll
    for (int at = 0; at < 2; ++at)
#pragma unroll
      for (int i = 0; i < 16; ++i) m = fmaxf(m, sacc[at][tt][i]);
    m = fmaxf(m, __shfl_xor(m, 32));
    float sum = 0.f;
#pragma unroll
    for (int at = 0; at < 2; ++at)
#pragma unroll
      for (int i = 0; i < 16; ++i) {
        const float e = __expf((sacc[at][tt][i] - m) * sp);
        sacc[at][tt][i] = e;
        sum += e;
      }
    sum += __shfl_xor(sum, 32);
    const float inv = w_s[32 * tt + c] / sum;
#pragma unroll
    for (int at = 0; at < 2; ++at)
#pragma unroll
      for (int pi = 0; pi < 8; ++pi)
        pkv[at][tt][pi] = pack2bf(sacc[at][tt][2 * pi] * inv, sacc[at][tt][2 * pi + 1] * inv);
  }

  // ---- PV
  f32x16 oac[2];
#pragma unroll
  for (int tt = 0; tt < 2; ++tt)
#pragma unroll
    for (int i = 0; i < 16; ++i) oac[tt][i] = 0.f;

  const int slotv = 16 + h * 4 + (c >> 3);
  const int lowv = (c & 7) * 2;
#pragma unroll
  for (int ks = 0; ks < 4; ++ks) {
    const int at = ks >> 1;
    const int ksb = 16 * ks + 8 * hl;
    FragU vf;
#pragma unroll
    for (int jj = 0; jj < 4; ++jj) {
      const unsigned lo =
          *(const ushort*)((const char*)kqv + (ksb + 2 * jj) * 512 + ((slotv ^ (2 * jj)) << 4) + lowv);
      const unsigned hi =
          *(const ushort*)((const char*)kqv + (ksb + 2 * jj + 1) * 512 + ((slotv ^ (2 * jj + 1)) << 4) + lowv);
      vf.u[jj] = lo | (hi << 16);
    }
#pragma unroll
    for (int tt = 0; tt < 2; ++tt) {
      // hl=0 SENDS pi base+2,3; hl=1 SENDS pi base+0,1.
      const int base = 4 * (ks & 1);
      const unsigned o0 = pkv[at][tt][base + 0];
      const unsigned o1 = pkv[at][tt][base + 1];
      const unsigned o2 = pkv[at][tt][base + 2];
      const unsigned o3 = pkv[at][tt][base + 3];
      const unsigned s0 = hl ? o0 : o2;
      const unsigned s1 = hl ? o1 : o3;
      const unsigned y0 = __shfl_xor(s0, 32);
      const unsigned y1 = __shfl_xor(s1, 32);
      FragU pf;
      pf.u[0] = hl ? y0 : o0;
      pf.u[1] = hl ? y1 : o1;
      pf.u[2] = hl ? o2 : y0;
      pf.u[3] = hl ? o3 : y1;
      oac[tt] = __builtin_amdgcn_mfma_f32_32x32x16_bf16(vf.s, pf.s, oac[tt], 0, 0, 0);
    }
  }

  // ---- store O^T -> wout[tok][128] bf16
#pragma unroll
  for (int tt = 0; tt < 2; ++tt) {
    ushort* wr = wout + ((bh + (size_t)k * 64 + 32 * tt + c) << 7) + h * 32 + 4 * hl;
#pragma unroll
    for (int pi = 0; pi < 4; ++pi) {
      uint2 pkw;
      pkw.x = pack2bf(oac[tt][4 * pi + 0], oac[tt][4 * pi + 1]);
      pkw.y = pack2bf(oac[tt][4 * pi + 2], oac[tt][4 * pi + 3]);
      *(uint2*)(wr + pi * 8) = pkw;
    }
  }
}

// ---------------------------------------------------------------------------
// Kernel 3: gather-based finalize (CSR walk), bf16 v + bf16 wout inputs.
// ---------------------------------------------------------------------------
__global__ __launch_bounds__(256) void final_gather(
    const ushort* __restrict__ qkvb, const ushort* __restrict__ wout,
    const float* __restrict__ sims, const int* __restrict__ cnt,
    const int* __restrict__ offs, const int* __restrict__ list,
    float* __restrict__ out) {
  __shared__ __align__(16) float res[64][132];
  __shared__ float invd[64];
  __shared__ int cnt_s[64], st_s[64];
  const int t = threadIdx.x;
  const int pos0 = xcd_swz(blockIdx.x) * 64;
  const int b = blockIdx.y;
  const size_t bh = (size_t)b << 14;

  if (t < 64) {
    const int p = pos0 + t;
    const int c = cnt[bh + p];
    cnt_s[t] = c;
    st_s[t] = offs[bh + p] - c;
  }
  // load v rows (qkv channels 128..255, bf16) into res — uint4/lane
#pragma unroll
  for (int it = 0; it < 4; ++it) {
    const int f = t + it * 256;
    const int row = f >> 4;
    const int c8 = (f & 15) * 8;
    const uint4 v = *(const uint4*)&qkvb[(bh + pos0 + row) * 256 + 128 + c8];
    res[row][c8 + 0] = bflo(v.x);
    res[row][c8 + 1] = bfhi(v.x);
    res[row][c8 + 2] = bflo(v.y);
    res[row][c8 + 3] = bfhi(v.y);
    res[row][c8 + 4] = bflo(v.z);
    res[row][c8 + 5] = bfhi(v.z);
    res[row][c8 + 6] = bflo(v.w);
    res[row][c8 + 7] = bfhi(v.w);
  }
  __syncthreads();

  if (t < 64) {
    float s = 0.f;
    const int n = cnt_s[t], st = st_s[t];
    for (int j = 0; j < n; ++j) {
      const int tok = list[bh + st + j];
      s += sims[bh + tok];
    }
    invd[t] = 1.0f / (1.0f + s);
  }
  __syncthreads();

  {
    const int w = t >> 6, l = t & 63;
    for (int p16 = 0; p16 < 16; ++p16) {
      const int p = w * 16 + p16;
      const int n = cnt_s[p], st = st_s[p];
      if (n) {
        float2 a = *(float2*)&res[p][l * 2];
        for (int j = 0; j < n; ++j) {
          const int tok = list[bh + st + j];
          const unsigned u = ((const unsigned*)(wout + ((bh + tok) << 7)))[l];
          a.x += bflo(u);
          a.y += bfhi(u);
        }
        res[p][l * 2] = a.x;
        res[p][l * 2 + 1] = a.y;
      }
    }
  }
  __syncthreads();

  {
    const int px = t & 63;
    const int cg = t >> 6;
    const float inv = invd[px];
#pragma unroll
    for (int it = 0; it < 32; ++it) {
      const int c = cg * 32 + it;
      out[(bh << 7) + (size_t)c * NHW + pos0 + px] = res[px][c] * inv;
    }
  }
}

// ---------------------------------------------------------------------------
extern "C" void kernel_launch(void* const* d_in, const int* in_sizes, int n_in,
                              void* d_out, int out_size, void* d_ws, size_t ws_size,
                              hipStream_t stream) {
  (void)in_sizes; (void)n_in; (void)out_size; (void)ws_size;
  const float* x     = (const float*)d_in[0];
  const float* jp    = (const float*)d_in[1];
  const float* sims  = (const float*)d_in[2];
  const float* gamma = (const float*)d_in[3];
  const float* beta  = (const float*)d_in[4];
  const float* Wq    = (const float*)d_in[5];
  const float* Wk    = (const float*)d_in[6];
  const float* Wv    = (const float*)d_in[7];
  const int* indices = (const int*)d_in[8];
  float* out = (float*)d_out;

  char* ws = (char*)d_ws;
  ushort* qkvb = (ushort*)ws;                       // [B][HW][256] bf16  67.1MB
  ushort* wout = (ushort*)(ws + 67108864);          // [B][HW][128] bf16  33.5MB
  ushort* Wb   = (ushort*)(ws + 100663296);         // [256][128] bf16    64KB
  int*    cnt  = (int*)(ws + 100728832);            // [B][HW]
  int*    offs = (int*)(ws + 101253120);            // [B][HW]
  int*    list = (int*)(ws + 101777408);            // [B][HW]

  zero_cnt_kernel<<<dim3(512), 256, 0, stream>>>(cnt);
  count_kernel<<<dim3(512), 256, 0, stream>>>(indices, cnt);
  wb_kernel<<<dim3(128), 256, 0, stream>>>(Wq, Wk, Wv, Wb);
  ln_proj_kernel<<<dim3(NHW / 64, NB), 256, 0, stream>>>(x, gamma, beta, Wb, qkvb);
  scan_kernel<<<dim3(NB), 256, 0, stream>>>(cnt, offs);
  fill_kernel<<<dim3(512), 256, 0, stream>>>(indices, offs, list);
  attn_kernel<<<dim3(NK, NB), 256, 0, stream>>>(qkvb, indices, sims, jp, wout);
  final_gather<<<dim3(NHW / 64, NB), 256, 0, stream>>>(qkvb, wout, sims, cnt,
                                                       offs, list, out);
}